// Round 6
// baseline (318.942 us; speedup 1.0000x reference)
//
#include <hip/hip_runtime.h>

#define T_SEQ 2048
#define D_MODEL 1024
#define NB 4
#define NH 16
#define HD 64

typedef __attribute__((ext_vector_type(8))) __bf16 bf16x8;
typedef __attribute__((ext_vector_type(4))) __bf16 bf16x4;
typedef __attribute__((ext_vector_type(4))) float f32x4;

__device__ __forceinline__ void gload_lds16(const void* g, void* l) {
  __builtin_amdgcn_global_load_lds((const __attribute__((address_space(1))) unsigned int*)g,
                                   (__attribute__((address_space(3))) unsigned int*)l,
                                   16, 0, 0);
}

__device__ __forceinline__ unsigned int pack_bf16_2(float e0, float e1) {
  unsigned short u0 = __builtin_bit_cast(unsigned short, (__bf16)e0);
  unsigned short u1 = __builtin_bit_cast(unsigned short, (__bf16)e1);
  return (unsigned int)u0 | ((unsigned int)u1 << 16);
}

// ---------------- convert fp32 -> bf16 (vectorized) ----------------
__global__ __launch_bounds__(256) void cvt_bf16_kernel(const float* __restrict__ s,
                                                       __bf16* __restrict__ d, int n) {
  int i = (blockIdx.x * 256 + threadIdx.x) * 8;
  if (i >= n) return;
  float4 a = *(const float4*)(s + i);
  float4 b = *(const float4*)(s + i + 4);
  bf16x8 v;
  v[0] = (__bf16)a.x; v[1] = (__bf16)a.y; v[2] = (__bf16)a.z; v[3] = (__bf16)a.w;
  v[4] = (__bf16)b.x; v[5] = (__bf16)b.y; v[6] = (__bf16)b.z; v[7] = (__bf16)b.w;
  *(bf16x8*)(d + i) = v;
}

// ---------------- transpose + convert: W[K][N] f32 -> Wt[N][K] bf16 ----------------
__global__ __launch_bounds__(256) void transpose_cvt_kernel(const float* __restrict__ W,
                                                            __bf16* __restrict__ Wt,
                                                            int K, int N) {
  __shared__ float t[32][33];
  int tx = threadIdx.x, ty = threadIdx.y;
  int n0 = blockIdx.x * 32, k0 = blockIdx.y * 32;
#pragma unroll
  for (int r = 0; r < 4; ++r)
    t[ty + r * 8][tx] = W[(size_t)(k0 + ty + r * 8) * N + n0 + tx];
  __syncthreads();
#pragma unroll
  for (int r = 0; r < 4; ++r)
    Wt[(size_t)(n0 + ty + r * 8) * K + k0 + tx] = (__bf16)t[tx][ty + r * 8];
}

// ---------------- extract V^T per head: qkv -> Vt[(b,h,dv)][t] bf16 ----------------
__global__ __launch_bounds__(256) void extract_vt_kernel(const __bf16* __restrict__ qkv,
                                                         __bf16* __restrict__ Vt) {
  __shared__ __bf16 t[32][34];
  int tx = threadIdx.x, ty = threadIdx.y;
  int tt = blockIdx.x * 32;   // seq offset
  int dt = blockIdx.y * 32;   // dv offset
  int bh = blockIdx.z;
  int b = bh >> 4, h = bh & 15;
#pragma unroll
  for (int r = 0; r < 4; ++r)
    t[ty + r * 8][tx] = qkv[(size_t)(b * T_SEQ + tt + ty + r * 8) * 3072 + 2048 + h * HD + dt + tx];
  __syncthreads();
#pragma unroll
  for (int r = 0; r < 4; ++r)
    Vt[(size_t)(bh * HD + dt + ty + r * 8) * T_SEQ + tt + tx] = t[tx][ty + r * 8];
}

// ---------------- GEMM: C[M][N] = A[M][K] * Bt[N][K]^T  (bf16 in, OutT out) ----------------
// 128x128 tile, BK=64, 4 waves, gload_lds width-16, XOR-swizzled LDS,
// bijective XCD-aware block swizzle (requires nwg % 8 == 0).
template <typename OutT>
__global__ __launch_bounds__(256) void gemm_bt(const __bf16* __restrict__ A,
                                               const __bf16* __restrict__ Bt,
                                               OutT* __restrict__ C,
                                               int M, int N, int K) {
  __shared__ __bf16 lA[128 * 64];
  __shared__ __bf16 lB[128 * 64];
  int tid = threadIdx.x;
  int lane = tid & 63, w = tid >> 6;
  int wm = w >> 1, wn = w & 1;
  int nwgx = gridDim.x;
  int lid = blockIdx.y * nwgx + blockIdx.x;
  int cpx = (nwgx * gridDim.y) >> 3;
  int swz = (lid & 7) * cpx + (lid >> 3);
  int bn = swz % nwgx, bm = swz / nwgx;
  f32x4 acc[4][4] = {};
  for (int kt = 0; kt < K; kt += 64) {
#pragma unroll
    for (int it = 0; it < 4; ++it) {
      int o = it * 4096 + tid * 16;          // byte offset in 16KB tile
      int row = o >> 7;                      // 128B per row (64 bf16)
      int ss = ((o >> 4) & 7) ^ (row & 7);   // inverse-swizzled source slot
      gload_lds16(A + (size_t)(bm * 128 + row) * K + kt + ss * 8, (char*)lA + o);
      gload_lds16(Bt + (size_t)(bn * 128 + row) * K + kt + ss * 8, (char*)lB + o);
    }
    __syncthreads();
    bf16x8 af[4][2], bfv[4][2];
#pragma unroll
    for (int i = 0; i < 4; ++i)
#pragma unroll
      for (int kk = 0; kk < 2; ++kk) {
        int ra = wm * 64 + i * 16 + (lane & 15);
        int sa = ((lane >> 4) + kk * 4) ^ (ra & 7);
        af[i][kk] = *(const bf16x8*)((const char*)lA + ra * 128 + sa * 16);
        int rb = wn * 64 + i * 16 + (lane & 15);
        int sb = ((lane >> 4) + kk * 4) ^ (rb & 7);
        bfv[i][kk] = *(const bf16x8*)((const char*)lB + rb * 128 + sb * 16);
      }
#pragma unroll
    for (int kk = 0; kk < 2; ++kk)
#pragma unroll
      for (int i = 0; i < 4; ++i)
#pragma unroll
        for (int j = 0; j < 4; ++j)
          acc[i][j] = __builtin_amdgcn_mfma_f32_16x16x32_bf16(af[i][kk], bfv[j][kk], acc[i][j], 0, 0, 0);
    __syncthreads();
  }
#pragma unroll
  for (int i = 0; i < 4; ++i)
#pragma unroll
    for (int j = 0; j < 4; ++j)
#pragma unroll
      for (int r = 0; r < 4; ++r) {
        int row = bm * 128 + wm * 64 + i * 16 + (lane >> 4) * 4 + r;
        int col = bn * 128 + wn * 64 + j * 16 + (lane & 15);
        C[(size_t)row * N + col] = (OutT)acc[i][j][r];
      }
}

// ---------------- causal flash attention v5: occupancy-first ----------------
// 2048 blocks (one 64-row q-tile each), 2 waves x 32 q-rows. Single-buffered
// K/V (LDS 16KB) + __launch_bounds__(128,4) -> 8 blocks/CU = 4 waves/SIMD;
// TLP hides stage latency (no intra-wave pipeline needed). Longest-first
// launch order (qt descends) balances the causal work. XCD-local decode:
// all 32 q-tiles of one (h,b) on one XCD (K/V stay L2-resident).
__global__ __launch_bounds__(128, 4) void attn_kernel(const __bf16* __restrict__ qkv,
                                                      const __bf16* __restrict__ Vt,
                                                      __bf16* __restrict__ Y) {
  __shared__ __bf16 lK[64 * 64];
  __shared__ __bf16 lV[64 * 64];
  int tid = threadIdx.x, lane = tid & 63, w = tid >> 6;  // w in {0,1}
  int q = lane & 15, g = lane >> 4;

  // decode: l -> (qt, h, b); qt descends with launch index; (h,b) fixed per XCD slot
  int l = blockIdx.x;
  int x = l & 7;            // XCD slot
  int i = l >> 3;           // 0..255
  int hbLocal = i & 7;      // 8 (h,b) pairs per XCD
  int qt = 31 - (i >> 3);   // longest-first
  int pairHB = x * 8 + hbLocal;
  int h = pairHB & 15, b = pairHB >> 4;

  const float SCALE = 0.125f * 1.44269504088896f;  // 1/sqrt(64) * log2(e)
  const f32x4 fzero = {0.f, 0.f, 0.f, 0.f};

  // Q fragments (B operand), 2 row-groups (qi), prescaled by SCALE
  bf16x8 qf[2][2];
#pragma unroll
  for (int qi = 0; qi < 2; ++qi) {
    const __bf16* qp =
        qkv + (size_t)(b * T_SEQ + qt * 64 + w * 32 + qi * 16 + q) * 3072 + h * HD;
    qf[qi][0] = *(const bf16x8*)(qp + g * 8);
    qf[qi][1] = *(const bf16x8*)(qp + 32 + g * 8);
#pragma unroll
    for (int kk = 0; kk < 2; ++kk)
#pragma unroll
      for (int jj = 0; jj < 8; ++jj)
        qf[qi][kk][jj] = (__bf16)((float)qf[qi][kk][jj] * SCALE);
  }

  float m[2] = {-INFINITY, -INFINITY}, lsum[2] = {0.f, 0.f};
  f32x4 yacc[2][4];
#pragma unroll
  for (int qi = 0; qi < 2; ++qi)
#pragma unroll
    for (int f = 0; f < 4; ++f) yacc[qi][f] = fzero;

#pragma unroll 1
  for (int kvt = 0; kvt <= qt; ++kvt) {
    // ---- stage K and V^T tiles (8KB each; 4 gload_lds x2 per thread) ----
#pragma unroll
    for (int it = 0; it < 4; ++it) {
      int o = it * 2048 + tid * 16;
      int row = o >> 7;
      int ss = ((o >> 4) & 7) ^ (row & 7);
      gload_lds16(qkv + (size_t)(b * T_SEQ + kvt * 64 + row) * 3072 + 1024 + h * HD + ss * 8,
                  (char*)lK + o);
      gload_lds16(Vt + (size_t)((b * NH + h) * HD + row) * T_SEQ + kvt * 64 + ss * 8,
                  (char*)lV + o);
    }
    __syncthreads();   // drains vmcnt: tile resident for all waves

    // ---- S^T = K Q^T : s[qi][f][r] = S[qrow(qi,q)][kv = f*16 + g*4 + r] ----
    f32x4 s[2][4];
#pragma unroll
    for (int qi = 0; qi < 2; ++qi)
#pragma unroll
      for (int f = 0; f < 4; ++f) s[qi][f] = fzero;
    const char* Kbase = (const char*)lK;
    __builtin_amdgcn_s_setprio(1);
#pragma unroll
    for (int kk = 0; kk < 2; ++kk)
#pragma unroll
      for (int f = 0; f < 4; ++f) {
        int rk = f * 16 + q;
        int sk = (g + kk * 4) ^ (rk & 7);
        bf16x8 kf = *(const bf16x8*)(Kbase + rk * 128 + sk * 16);
#pragma unroll
        for (int qi = 0; qi < 2; ++qi)
          s[qi][f] = __builtin_amdgcn_mfma_f32_16x16x32_bf16(kf, qf[qi][kk], s[qi][f], 0, 0, 0);
      }
    __builtin_amdgcn_s_setprio(0);

    // ---- causal mask (diagonal tile only) ----
    if (kvt == qt) {
#pragma unroll
      for (int qi = 0; qi < 2; ++qi) {
        int qloc = w * 32 + qi * 16 + q;
#pragma unroll
        for (int f = 0; f < 4; ++f)
#pragma unroll
          for (int r = 0; r < 4; ++r)
            if (f * 16 + g * 4 + r > qloc) s[qi][f][r] = -INFINITY;
      }
    }

    // ---- row max (local tree + 2 shfl) per qi ----
    float mx[2];
#pragma unroll
    for (int qi = 0; qi < 2; ++qi) {
      float v = fmaxf(fmaxf(fmaxf(s[qi][0][0], s[qi][0][1]), fmaxf(s[qi][0][2], s[qi][0][3])),
                      fmaxf(fmaxf(s[qi][1][0], s[qi][1][1]), fmaxf(s[qi][1][2], s[qi][1][3])));
      v = fmaxf(v, fmaxf(fmaxf(fmaxf(s[qi][2][0], s[qi][2][1]), fmaxf(s[qi][2][2], s[qi][2][3])),
                         fmaxf(fmaxf(s[qi][3][0], s[qi][3][1]), fmaxf(s[qi][3][2], s[qi][3][3]))));
      v = fmaxf(v, __shfl_xor(v, 16, 64));
      v = fmaxf(v, __shfl_xor(v, 32, 64));
      mx[qi] = v;
    }

    // ---- defer-max rescale: only when growth exceeds THR=8 (P bounded by 2^8) ----
    float growth = fmaxf(mx[0] - m[0], mx[1] - m[1]);
    if (__any(growth > 8.0f)) {
#pragma unroll
      for (int qi = 0; qi < 2; ++qi) {
        float mn = fmaxf(m[qi], mx[qi]);
        float al = exp2f(m[qi] - mn);
        m[qi] = mn;
        lsum[qi] *= al;
#pragma unroll
        for (int r = 0; r < 4; ++r) {
          float ar = __shfl(al, g * 4 + r, 64);
#pragma unroll
          for (int f = 0; f < 4; ++f) yacc[qi][f][r] *= ar;
        }
      }
    }

    // ---- P = exp2(S - m), packed to bf16 words ----
    unsigned int Wd[2][4][2];
#pragma unroll
    for (int qi = 0; qi < 2; ++qi) {
      float ps = 0.f;
#pragma unroll
      for (int f = 0; f < 4; ++f)
#pragma unroll
        for (int hh = 0; hh < 2; ++hh) {
          float e0 = exp2f(s[qi][f][2 * hh] - m[qi]);
          float e1 = exp2f(s[qi][f][2 * hh + 1] - m[qi]);
          ps += e0 + e1;
          Wd[qi][f][hh] = pack_bf16_2(e0, e1);
        }
      lsum[qi] += ps;
    }

    // ---- redistribute P words into PV A-operand frags ----
    int srcA = ((g & 1) << 5) | q;
    int srcB = srcA + 16;
    bool hisel = (g >= 2);
    bf16x8 pa[2][2];
#pragma unroll
    for (int qi = 0; qi < 2; ++qi)
#pragma unroll
      for (int kk = 0; kk < 2; ++kk) {
        unsigned int pw[4];
#pragma unroll
        for (int t = 0; t < 4; ++t) {
          int src = (t < 2) ? srcA : srcB;
          unsigned int c0 = (unsigned int)__shfl((int)Wd[qi][2 * kk][t & 1], src, 64);
          unsigned int c1 = (unsigned int)__shfl((int)Wd[qi][2 * kk + 1][t & 1], src, 64);
          pw[t] = hisel ? c1 : c0;
        }
        uint4 u = make_uint4(pw[0], pw[1], pw[2], pw[3]);
        pa[qi][kk] = __builtin_bit_cast(bf16x8, u);
      }

    // ---- O += P V ----
    const char* Vbase = (const char*)lV;
    __builtin_amdgcn_s_setprio(1);
#pragma unroll
    for (int kk = 0; kk < 2; ++kk)
#pragma unroll
      for (int f = 0; f < 4; ++f) {
        int rv = f * 16 + q;
        int sv2 = (g + kk * 4) ^ (rv & 7);
        bf16x8 vf = *(const bf16x8*)(Vbase + rv * 128 + sv2 * 16);
#pragma unroll
        for (int qi = 0; qi < 2; ++qi)
          yacc[qi][f] = __builtin_amdgcn_mfma_f32_16x16x32_bf16(pa[qi][kk], vf, yacc[qi][f], 0, 0, 0);
      }
    __builtin_amdgcn_s_setprio(0);

    __syncthreads();   // all waves done reading before next stage overwrites
  }

  // ---- epilogue ----
#pragma unroll
  for (int qi = 0; qi < 2; ++qi) {
    float ls = lsum[qi];
    ls += __shfl_xor(ls, 16, 64);
    ls += __shfl_xor(ls, 32, 64);
    float linv = 1.0f / ls;
    int qrow = qt * 64 + w * 32 + qi * 16 + g * 4;
#pragma unroll
    for (int r = 0; r < 4; ++r) {
      float lr = __shfl(linv, g * 4 + r, 64);
#pragma unroll
      for (int f = 0; f < 4; ++f) {
        Y[(size_t)(b * T_SEQ + qrow + r) * D_MODEL + h * HD + f * 16 + q] =
            (__bf16)(yacc[qi][f][r] * lr);
      }
    }
  }
}

// ---------------- launcher ----------------
extern "C" void kernel_launch(void* const* d_in, const int* in_sizes, int n_in,
                              void* d_out, int out_size, void* d_ws, size_t ws_size,
                              hipStream_t stream) {
  const float* x = (const float*)d_in[0];      // [4,2048,1024]
  const float* Wqkv = (const float*)d_in[1];   // [1024,3072]
  const float* Wproj = (const float*)d_in[2];  // [1024,1024]
  float* out = (float*)d_out;                  // [4,2048,1024]
  char* ws = (char*)d_ws;

  __bf16* Xbf     = (__bf16*)(ws);                       // 16.78 MB
  __bf16* Wqkv_t  = (__bf16*)(ws + 16777216);            // 6.29 MB  [3072][1024]
  __bf16* Wproj_t = (__bf16*)(ws + 23068672);            // 2.10 MB  [1024][1024]
  __bf16* QKV     = (__bf16*)(ws + 25165824);            // 50.33 MB [8192][3072]
  __bf16* Vt      = (__bf16*)(ws + 75497472);            // 16.78 MB [(b,h,dv)][2048]
  __bf16* Yb      = (__bf16*)(ws + 92274688);            // 16.78 MB [8192][1024]

  cvt_bf16_kernel<<<4096, 256, 0, stream>>>(x, Xbf, NB * T_SEQ * D_MODEL);
  transpose_cvt_kernel<<<dim3(96, 32), dim3(32, 8), 0, stream>>>(Wqkv, Wqkv_t, 1024, 3072);
  transpose_cvt_kernel<<<dim3(32, 32), dim3(32, 8), 0, stream>>>(Wproj, Wproj_t, 1024, 1024);
  gemm_bt<__bf16><<<dim3(24, 64), 256, 0, stream>>>(Xbf, Wqkv_t, QKV, 8192, 3072, 1024);
  extract_vt_kernel<<<dim3(64, 2, 64), dim3(32, 8), 0, stream>>>(QKV, Vt);
  attn_kernel<<<2048, 128, 0, stream>>>(QKV, Vt, Yb);
  gemm_bt<float><<<dim3(8, 64), 256, 0, stream>>>(Yb, Wproj_t, out, 8192, 1024, 1024);
}

// Round 8
// 305.735 us; speedup vs baseline: 1.0432x; 1.0432x over previous
//
#include <hip/hip_runtime.h>

#define T_SEQ 2048
#define D_MODEL 1024
#define NB 4
#define NH 16
#define HD 64

typedef __attribute__((ext_vector_type(8))) __bf16 bf16x8;
typedef __attribute__((ext_vector_type(4))) __bf16 bf16x4;
typedef __attribute__((ext_vector_type(4))) float f32x4;

__device__ __forceinline__ void gload_lds16(const void* g, void* l) {
  __builtin_amdgcn_global_load_lds((const __attribute__((address_space(1))) unsigned int*)g,
                                   (__attribute__((address_space(3))) unsigned int*)l,
                                   16, 0, 0);
}

__device__ __forceinline__ unsigned int pack_bf16_2(float e0, float e1) {
  unsigned short u0 = __builtin_bit_cast(unsigned short, (__bf16)e0);
  unsigned short u1 = __builtin_bit_cast(unsigned short, (__bf16)e1);
  return (unsigned int)u0 | ((unsigned int)u1 << 16);
}

// ---------------- convert fp32 -> bf16 (vectorized) ----------------
__global__ __launch_bounds__(256) void cvt_bf16_kernel(const float* __restrict__ s,
                                                       __bf16* __restrict__ d, int n) {
  int i = (blockIdx.x * 256 + threadIdx.x) * 8;
  if (i >= n) return;
  float4 a = *(const float4*)(s + i);
  float4 b = *(const float4*)(s + i + 4);
  bf16x8 v;
  v[0] = (__bf16)a.x; v[1] = (__bf16)a.y; v[2] = (__bf16)a.z; v[3] = (__bf16)a.w;
  v[4] = (__bf16)b.x; v[5] = (__bf16)b.y; v[6] = (__bf16)b.z; v[7] = (__bf16)b.w;
  *(bf16x8*)(d + i) = v;
}

// ---------------- transpose + convert: W[K][N] f32 -> Wt[N][K] bf16 ----------------
__global__ __launch_bounds__(256) void transpose_cvt_kernel(const float* __restrict__ W,
                                                            __bf16* __restrict__ Wt,
                                                            int K, int N) {
  __shared__ float t[32][33];
  int tx = threadIdx.x, ty = threadIdx.y;
  int n0 = blockIdx.x * 32, k0 = blockIdx.y * 32;
#pragma unroll
  for (int r = 0; r < 4; ++r)
    t[ty + r * 8][tx] = W[(size_t)(k0 + ty + r * 8) * N + n0 + tx];
  __syncthreads();
#pragma unroll
  for (int r = 0; r < 4; ++r)
    Wt[(size_t)(n0 + ty + r * 8) * K + k0 + tx] = (__bf16)t[tx][ty + r * 8];
}

// ---------------- extract V^T per head: qkv -> Vt[(b,h,dv)][t] bf16 ----------------
__global__ __launch_bounds__(256) void extract_vt_kernel(const __bf16* __restrict__ qkv,
                                                         __bf16* __restrict__ Vt) {
  __shared__ __bf16 t[32][34];
  int tx = threadIdx.x, ty = threadIdx.y;
  int tt = blockIdx.x * 32;   // seq offset
  int dt = blockIdx.y * 32;   // dv offset
  int bh = blockIdx.z;
  int b = bh >> 4, h = bh & 15;
#pragma unroll
  for (int r = 0; r < 4; ++r)
    t[ty + r * 8][tx] = qkv[(size_t)(b * T_SEQ + tt + ty + r * 8) * 3072 + 2048 + h * HD + dt + tx];
  __syncthreads();
#pragma unroll
  for (int r = 0; r < 4; ++r)
    Vt[(size_t)(bh * HD + dt + ty + r * 8) * T_SEQ + tt + tx] = t[tx][ty + r * 8];
}

// ---------------- GEMM: C[M][N] = A[M][K] * Bt[N][K]^T  (bf16 in, OutT out) ----------------
template <typename OutT>
__global__ __launch_bounds__(256) void gemm_bt(const __bf16* __restrict__ A,
                                               const __bf16* __restrict__ Bt,
                                               OutT* __restrict__ C,
                                               int M, int N, int K) {
  __shared__ __bf16 lA[128 * 64];
  __shared__ __bf16 lB[128 * 64];
  int tid = threadIdx.x;
  int lane = tid & 63, w = tid >> 6;
  int wm = w >> 1, wn = w & 1;
  int nwgx = gridDim.x;
  int lid = blockIdx.y * nwgx + blockIdx.x;
  int cpx = (nwgx * gridDim.y) >> 3;
  int swz = (lid & 7) * cpx + (lid >> 3);
  int bn = swz % nwgx, bm = swz / nwgx;
  f32x4 acc[4][4] = {};
  for (int kt = 0; kt < K; kt += 64) {
#pragma unroll
    for (int it = 0; it < 4; ++it) {
      int o = it * 4096 + tid * 16;          // byte offset in 16KB tile
      int row = o >> 7;                      // 128B per row (64 bf16)
      int ss = ((o >> 4) & 7) ^ (row & 7);   // inverse-swizzled source slot
      gload_lds16(A + (size_t)(bm * 128 + row) * K + kt + ss * 8, (char*)lA + o);
      gload_lds16(Bt + (size_t)(bn * 128 + row) * K + kt + ss * 8, (char*)lB + o);
    }
    __syncthreads();
    bf16x8 af[4][2], bfv[4][2];
#pragma unroll
    for (int i = 0; i < 4; ++i)
#pragma unroll
      for (int kk = 0; kk < 2; ++kk) {
        int ra = wm * 64 + i * 16 + (lane & 15);
        int sa = ((lane >> 4) + kk * 4) ^ (ra & 7);
        af[i][kk] = *(const bf16x8*)((const char*)lA + ra * 128 + sa * 16);
        int rb = wn * 64 + i * 16 + (lane & 15);
        int sb = ((lane >> 4) + kk * 4) ^ (rb & 7);
        bfv[i][kk] = *(const bf16x8*)((const char*)lB + rb * 128 + sb * 16);
      }
#pragma unroll
    for (int kk = 0; kk < 2; ++kk)
#pragma unroll
      for (int i = 0; i < 4; ++i)
#pragma unroll
        for (int j = 0; j < 4; ++j)
          acc[i][j] = __builtin_amdgcn_mfma_f32_16x16x32_bf16(af[i][kk], bfv[j][kk], acc[i][j], 0, 0, 0);
    __syncthreads();
  }
#pragma unroll
  for (int i = 0; i < 4; ++i)
#pragma unroll
    for (int j = 0; j < 4; ++j)
#pragma unroll
      for (int r = 0; r < 4; ++r) {
        int row = bm * 128 + wm * 64 + i * 16 + (lane >> 4) * 4 + r;
        int col = bn * 128 + wn * 64 + j * 16 + (lane & 15);
        C[(size_t)row * N + col] = (OutT)acc[i][j][r];
      }
}

// ---------------- causal flash attention v6: pair-parallel waves ----------------
// 1024 blocks x 256 threads. Waves 0-1 own q-tile qtHi=31-p, waves 2-3 own
// qtLo=p; one shared K/V stream over kv in [0, qtHi] (qtLo's range is a
// prefix). Per-wave 32 q-rows (2 A-frags). Double-buffered K/V, counted
// vmcnt; swapped-QK in-register softmax; defer-max (THR=8). LDS 32KB,
// 4 blocks/CU x 4 waves = 16 waves/CU. XCD-local (h,b) decode.
__global__ __launch_bounds__(256, 4) void attn_kernel(const __bf16* __restrict__ qkv,
                                                      const __bf16* __restrict__ Vt,
                                                      __bf16* __restrict__ Y) {
  __shared__ __bf16 lK[2][64 * 64];
  __shared__ __bf16 lV[2][64 * 64];
  int tid = threadIdx.x, lane = tid & 63, w = tid >> 6;  // w in 0..3
  int q = lane & 15, g = lane >> 4;
  int wl = w & 1;  // wave index within its q-tile pair

  // XCD-aware decode: l -> (p, h, b); all 16 p-blocks of one (h,b) per XCD
  int l = blockIdx.x;
  int pairHB = ((l & 7) << 3) | (l >> 7);
  int p = (l >> 3) & 15;
  int h = pairHB & 15, b = pairHB >> 4;
  int qtHi = 31 - p;
  int myqt = (w < 2) ? qtHi : p;

  const float SCALE = 0.125f * 1.44269504088896f;  // 1/sqrt(64) * log2(e)
  const f32x4 fzero = {0.f, 0.f, 0.f, 0.f};

  // Q fragments (B operand), 2 row-groups (qi), prescaled by SCALE
  bf16x8 qf[2][2];
#pragma unroll
  for (int qi = 0; qi < 2; ++qi) {
    const __bf16* qp =
        qkv + (size_t)(b * T_SEQ + myqt * 64 + wl * 32 + qi * 16 + q) * 3072 + h * HD;
    qf[qi][0] = *(const bf16x8*)(qp + g * 8);
    qf[qi][1] = *(const bf16x8*)(qp + 32 + g * 8);
#pragma unroll
    for (int kk = 0; kk < 2; ++kk)
#pragma unroll
      for (int jj = 0; jj < 8; ++jj)
        qf[qi][kk][jj] = (__bf16)((float)qf[qi][kk][jj] * SCALE);
  }

  float m[2] = {-INFINITY, -INFINITY}, lsum[2] = {0.f, 0.f};
  f32x4 yacc[2][4];
#pragma unroll
  for (int qi = 0; qi < 2; ++qi)
#pragma unroll
    for (int f = 0; f < 4; ++f) yacc[qi][f] = fzero;

  // drain Q loads so vmcnt accounting below is exact
  asm volatile("s_waitcnt vmcnt(0)" ::: "memory");
  __builtin_amdgcn_sched_barrier(0);

  auto STAGE = [&](int kvt, int bi) {
#pragma unroll
    for (int it = 0; it < 2; ++it) {
      int o = it * 4096 + tid * 16;
      int row = o >> 7;
      int ss = ((o >> 4) & 7) ^ (row & 7);
      gload_lds16(qkv + (size_t)(b * T_SEQ + kvt * 64 + row) * 3072 + 1024 + h * HD + ss * 8,
                  (char*)lK[bi] + o);
      gload_lds16(Vt + (size_t)((b * NH + h) * HD + row) * T_SEQ + kvt * 64 + ss * 8,
                  (char*)lV[bi] + o);
    }
  };

  STAGE(0, 0);

#pragma unroll 1
  for (int kvt = 0; kvt <= qtHi; ++kvt) {
    int cur = kvt & 1;
    if (kvt < qtHi) {
      STAGE(kvt + 1, cur ^ 1);
      asm volatile("s_waitcnt vmcnt(4)" ::: "memory");  // cur landed; prefetch in flight
    } else {
      asm volatile("s_waitcnt vmcnt(0)" ::: "memory");
    }
    __builtin_amdgcn_sched_barrier(0);
    __builtin_amdgcn_s_barrier();
    __builtin_amdgcn_sched_barrier(0);

    if (kvt <= myqt) {  // wave-uniform guard: w23 idle for kvt > qtLo
      // ---- S^T = K Q^T : s[qi][f][r] = S[qrow(qi,q)][kv = f*16 + g*4 + r] ----
      f32x4 s[2][4];
#pragma unroll
      for (int qi = 0; qi < 2; ++qi)
#pragma unroll
        for (int f = 0; f < 4; ++f) s[qi][f] = fzero;
      const char* Kbase = (const char*)lK[cur];
      __builtin_amdgcn_s_setprio(1);
#pragma unroll
      for (int kk = 0; kk < 2; ++kk)
#pragma unroll
        for (int f = 0; f < 4; ++f) {
          int rk = f * 16 + q;
          int sk = (g + kk * 4) ^ (rk & 7);
          bf16x8 kf = *(const bf16x8*)(Kbase + rk * 128 + sk * 16);
#pragma unroll
          for (int qi = 0; qi < 2; ++qi)
            s[qi][f] = __builtin_amdgcn_mfma_f32_16x16x32_bf16(kf, qf[qi][kk], s[qi][f], 0, 0, 0);
        }
      __builtin_amdgcn_s_setprio(0);

      // ---- causal mask (diagonal tile only) ----
      if (kvt == myqt) {
#pragma unroll
        for (int qi = 0; qi < 2; ++qi) {
          int qloc = wl * 32 + qi * 16 + q;
#pragma unroll
          for (int f = 0; f < 4; ++f)
#pragma unroll
            for (int r = 0; r < 4; ++r)
              if (f * 16 + g * 4 + r > qloc) s[qi][f][r] = -INFINITY;
        }
      }

      // ---- row max (local tree + 2 shfl) per qi ----
      float mx[2];
#pragma unroll
      for (int qi = 0; qi < 2; ++qi) {
        float v = fmaxf(fmaxf(fmaxf(s[qi][0][0], s[qi][0][1]), fmaxf(s[qi][0][2], s[qi][0][3])),
                        fmaxf(fmaxf(s[qi][1][0], s[qi][1][1]), fmaxf(s[qi][1][2], s[qi][1][3])));
        v = fmaxf(v, fmaxf(fmaxf(fmaxf(s[qi][2][0], s[qi][2][1]), fmaxf(s[qi][2][2], s[qi][2][3])),
                           fmaxf(fmaxf(s[qi][3][0], s[qi][3][1]), fmaxf(s[qi][3][2], s[qi][3][3]))));
        v = fmaxf(v, __shfl_xor(v, 16, 64));
        v = fmaxf(v, __shfl_xor(v, 32, 64));
        mx[qi] = v;
      }

      // ---- defer-max rescale: only when growth exceeds THR=8 ----
      float growth = fmaxf(mx[0] - m[0], mx[1] - m[1]);
      if (__any(growth > 8.0f)) {
#pragma unroll
        for (int qi = 0; qi < 2; ++qi) {
          float mn = fmaxf(m[qi], mx[qi]);
          float al = exp2f(m[qi] - mn);
          m[qi] = mn;
          lsum[qi] *= al;
#pragma unroll
          for (int r = 0; r < 4; ++r) {
            float ar = __shfl(al, g * 4 + r, 64);
#pragma unroll
            for (int f = 0; f < 4; ++f) yacc[qi][f][r] *= ar;
          }
        }
      }

      // ---- P = exp2(S - m), packed to bf16 words ----
      unsigned int Wd[2][4][2];
#pragma unroll
      for (int qi = 0; qi < 2; ++qi) {
        float ps = 0.f;
#pragma unroll
        for (int f = 0; f < 4; ++f)
#pragma unroll
          for (int hh = 0; hh < 2; ++hh) {
            float e0 = exp2f(s[qi][f][2 * hh] - m[qi]);
            float e1 = exp2f(s[qi][f][2 * hh + 1] - m[qi]);
            ps += e0 + e1;
            Wd[qi][f][hh] = pack_bf16_2(e0, e1);
          }
        lsum[qi] += ps;
      }

      // ---- redistribute P words into PV A-operand frags ----
      int srcA = ((g & 1) << 5) | q;
      int srcB = srcA + 16;
      bool hisel = (g >= 2);
      bf16x8 pa[2][2];
#pragma unroll
      for (int qi = 0; qi < 2; ++qi)
#pragma unroll
        for (int kk = 0; kk < 2; ++kk) {
          unsigned int pw[4];
#pragma unroll
          for (int t = 0; t < 4; ++t) {
            int src = (t < 2) ? srcA : srcB;
            unsigned int c0 = (unsigned int)__shfl((int)Wd[qi][2 * kk][t & 1], src, 64);
            unsigned int c1 = (unsigned int)__shfl((int)Wd[qi][2 * kk + 1][t & 1], src, 64);
            pw[t] = hisel ? c1 : c0;
          }
          uint4 u = make_uint4(pw[0], pw[1], pw[2], pw[3]);
          pa[qi][kk] = __builtin_bit_cast(bf16x8, u);
        }

      // ---- O += P V ----
      const char* Vbase = (const char*)lV[cur];
      __builtin_amdgcn_s_setprio(1);
#pragma unroll
      for (int kk = 0; kk < 2; ++kk)
#pragma unroll
        for (int f = 0; f < 4; ++f) {
          int rv = f * 16 + q;
          int sv2 = (g + kk * 4) ^ (rv & 7);
          bf16x8 vf = *(const bf16x8*)(Vbase + rv * 128 + sv2 * 16);
#pragma unroll
          for (int qi = 0; qi < 2; ++qi)
            yacc[qi][f] = __builtin_amdgcn_mfma_f32_16x16x32_bf16(pa[qi][kk], vf, yacc[qi][f], 0, 0, 0);
        }
      __builtin_amdgcn_s_setprio(0);
    }

    // all waves done reading cur before next iter's STAGE overwrites the other buffer
    __builtin_amdgcn_sched_barrier(0);
    asm volatile("s_waitcnt lgkmcnt(0)" ::: "memory");
    __builtin_amdgcn_s_barrier();
    __builtin_amdgcn_sched_barrier(0);
  }

  // ---- epilogue ----
#pragma unroll
  for (int qi = 0; qi < 2; ++qi) {
    float ls = lsum[qi];
    ls += __shfl_xor(ls, 16, 64);
    ls += __shfl_xor(ls, 32, 64);
    float linv = 1.0f / ls;
    int qrow = myqt * 64 + wl * 32 + qi * 16 + g * 4;
#pragma unroll
    for (int r = 0; r < 4; ++r) {
      float lr = __shfl(linv, g * 4 + r, 64);
#pragma unroll
      for (int f = 0; f < 4; ++f) {
        Y[(size_t)(b * T_SEQ + qrow + r) * D_MODEL + h * HD + f * 16 + q] =
            (__bf16)(yacc[qi][f][r] * lr);
      }
    }
  }
}

// ---------------- launcher ----------------
extern "C" void kernel_launch(void* const* d_in, const int* in_sizes, int n_in,
                              void* d_out, int out_size, void* d_ws, size_t ws_size,
                              hipStream_t stream) {
  const float* x = (const float*)d_in[0];      // [4,2048,1024]
  const float* Wqkv = (const float*)d_in[1];   // [1024,3072]
  const float* Wproj = (const float*)d_in[2];  // [1024,1024]
  float* out = (float*)d_out;                  // [4,2048,1024]
  char* ws = (char*)d_ws;

  __bf16* Xbf     = (__bf16*)(ws);                       // 16.78 MB
  __bf16* Wqkv_t  = (__bf16*)(ws + 16777216);            // 6.29 MB  [3072][1024]
  __bf16* Wproj_t = (__bf16*)(ws + 23068672);            // 2.10 MB  [1024][1024]
  __bf16* QKV     = (__bf16*)(ws + 25165824);            // 50.33 MB [8192][3072]
  __bf16* Vt      = (__bf16*)(ws + 75497472);            // 16.78 MB [(b,h,dv)][2048]
  __bf16* Yb      = (__bf16*)(ws + 92274688);            // 16.78 MB [8192][1024]

  cvt_bf16_kernel<<<4096, 256, 0, stream>>>(x, Xbf, NB * T_SEQ * D_MODEL);
  transpose_cvt_kernel<<<dim3(96, 32), dim3(32, 8), 0, stream>>>(Wqkv, Wqkv_t, 1024, 3072);
  transpose_cvt_kernel<<<dim3(32, 32), dim3(32, 8), 0, stream>>>(Wproj, Wproj_t, 1024, 1024);
  gemm_bt<__bf16><<<dim3(24, 64), 256, 0, stream>>>(Xbf, Wqkv_t, QKV, 8192, 3072, 1024);
  extract_vt_kernel<<<dim3(64, 2, 64), dim3(32, 8), 0, stream>>>(QKV, Vt);
  attn_kernel<<<1024, 256, 0, stream>>>(QKV, Vt, Yb);
  gemm_bt<float><<<dim3(8, 64), 256, 0, stream>>>(Yb, Wproj_t, out, 8192, 1024, 1024);
}

// Round 9
// 277.546 us; speedup vs baseline: 1.1491x; 1.1016x over previous
//
#include <hip/hip_runtime.h>

#define T_SEQ 2048
#define D_MODEL 1024
#define NB 4
#define NH 16
#define HD 64

typedef __attribute__((ext_vector_type(8))) __bf16 bf16x8;
typedef __attribute__((ext_vector_type(4))) __bf16 bf16x4;
typedef __attribute__((ext_vector_type(4))) float f32x4;

__device__ __forceinline__ void gload_lds16(const void* g, void* l) {
  __builtin_amdgcn_global_load_lds((const __attribute__((address_space(1))) unsigned int*)g,
                                   (__attribute__((address_space(3))) unsigned int*)l,
                                   16, 0, 0);
}

__device__ __forceinline__ unsigned int pack_bf16_2(float e0, float e1) {
  unsigned short u0 = __builtin_bit_cast(unsigned short, (__bf16)e0);
  unsigned short u1 = __builtin_bit_cast(unsigned short, (__bf16)e1);
  return (unsigned int)u0 | ((unsigned int)u1 << 16);
}

// ---------------- convert fp32 -> bf16 (vectorized) ----------------
__global__ __launch_bounds__(256) void cvt_bf16_kernel(const float* __restrict__ s,
                                                       __bf16* __restrict__ d, int n) {
  int i = (blockIdx.x * 256 + threadIdx.x) * 8;
  if (i >= n) return;
  float4 a = *(const float4*)(s + i);
  float4 b = *(const float4*)(s + i + 4);
  bf16x8 v;
  v[0] = (__bf16)a.x; v[1] = (__bf16)a.y; v[2] = (__bf16)a.z; v[3] = (__bf16)a.w;
  v[4] = (__bf16)b.x; v[5] = (__bf16)b.y; v[6] = (__bf16)b.z; v[7] = (__bf16)b.w;
  *(bf16x8*)(d + i) = v;
}

// ---------------- transpose + convert: W[K][N] f32 -> Wt[N][K] bf16 ----------------
__global__ __launch_bounds__(256) void transpose_cvt_kernel(const float* __restrict__ W,
                                                            __bf16* __restrict__ Wt,
                                                            int K, int N) {
  __shared__ float t[32][33];
  int tx = threadIdx.x, ty = threadIdx.y;
  int n0 = blockIdx.x * 32, k0 = blockIdx.y * 32;
#pragma unroll
  for (int r = 0; r < 4; ++r)
    t[ty + r * 8][tx] = W[(size_t)(k0 + ty + r * 8) * N + n0 + tx];
  __syncthreads();
#pragma unroll
  for (int r = 0; r < 4; ++r)
    Wt[(size_t)(n0 + ty + r * 8) * K + k0 + tx] = (__bf16)t[tx][ty + r * 8];
}

// ---------------- extract V^T per head: qkv -> Vt[(b,h,dv)][t] bf16 ----------------
__global__ __launch_bounds__(256) void extract_vt_kernel(const __bf16* __restrict__ qkv,
                                                         __bf16* __restrict__ Vt) {
  __shared__ __bf16 t[32][34];
  int tx = threadIdx.x, ty = threadIdx.y;
  int tt = blockIdx.x * 32;   // seq offset
  int dt = blockIdx.y * 32;   // dv offset
  int bh = blockIdx.z;
  int b = bh >> 4, h = bh & 15;
#pragma unroll
  for (int r = 0; r < 4; ++r)
    t[ty + r * 8][tx] = qkv[(size_t)(b * T_SEQ + tt + ty + r * 8) * 3072 + 2048 + h * HD + dt + tx];
  __syncthreads();
#pragma unroll
  for (int r = 0; r < 4; ++r)
    Vt[(size_t)(bh * HD + dt + ty + r * 8) * T_SEQ + tt + tx] = t[tx][ty + r * 8];
}

// ---------------- GEMM: C[M][N] = A[M][K] * Bt[N][K]^T  (bf16 in, OutT out) ----------------
template <typename OutT>
__global__ __launch_bounds__(256) void gemm_bt(const __bf16* __restrict__ A,
                                               const __bf16* __restrict__ Bt,
                                               OutT* __restrict__ C,
                                               int M, int N, int K) {
  __shared__ __bf16 lA[128 * 64];
  __shared__ __bf16 lB[128 * 64];
  int tid = threadIdx.x;
  int lane = tid & 63, w = tid >> 6;
  int wm = w >> 1, wn = w & 1;
  int nwgx = gridDim.x;
  int lid = blockIdx.y * nwgx + blockIdx.x;
  int cpx = (nwgx * gridDim.y) >> 3;
  int swz = (lid & 7) * cpx + (lid >> 3);
  int bn = swz % nwgx, bm = swz / nwgx;
  f32x4 acc[4][4] = {};
  for (int kt = 0; kt < K; kt += 64) {
#pragma unroll
    for (int it = 0; it < 4; ++it) {
      int o = it * 4096 + tid * 16;          // byte offset in 16KB tile
      int row = o >> 7;                      // 128B per row (64 bf16)
      int ss = ((o >> 4) & 7) ^ (row & 7);   // inverse-swizzled source slot
      gload_lds16(A + (size_t)(bm * 128 + row) * K + kt + ss * 8, (char*)lA + o);
      gload_lds16(Bt + (size_t)(bn * 128 + row) * K + kt + ss * 8, (char*)lB + o);
    }
    __syncthreads();
    bf16x8 af[4][2], bfv[4][2];
#pragma unroll
    for (int i = 0; i < 4; ++i)
#pragma unroll
      for (int kk = 0; kk < 2; ++kk) {
        int ra = wm * 64 + i * 16 + (lane & 15);
        int sa = ((lane >> 4) + kk * 4) ^ (ra & 7);
        af[i][kk] = *(const bf16x8*)((const char*)lA + ra * 128 + sa * 16);
        int rb = wn * 64 + i * 16 + (lane & 15);
        int sb = ((lane >> 4) + kk * 4) ^ (rb & 7);
        bfv[i][kk] = *(const bf16x8*)((const char*)lB + rb * 128 + sb * 16);
      }
#pragma unroll
    for (int kk = 0; kk < 2; ++kk)
#pragma unroll
      for (int i = 0; i < 4; ++i)
#pragma unroll
        for (int j = 0; j < 4; ++j)
          acc[i][j] = __builtin_amdgcn_mfma_f32_16x16x32_bf16(af[i][kk], bfv[j][kk], acc[i][j], 0, 0, 0);
    __syncthreads();
  }
#pragma unroll
  for (int i = 0; i < 4; ++i)
#pragma unroll
    for (int j = 0; j < 4; ++j)
#pragma unroll
      for (int r = 0; r < 4; ++r) {
        int row = bm * 128 + wm * 64 + i * 16 + (lane >> 4) * 4 + r;
        int col = bn * 128 + wn * 64 + j * 16 + (lane & 15);
        C[(size_t)row * N + col] = (OutT)acc[i][j][r];
      }
}

// ---------------- causal flash attention v7: r5 schedule, 4-wave split ----------------
// 1024 blocks x 256 threads. Paired q-tiles {31-p, p} (2 passes): every block
// = 33 kv tiles, ALL 4 waves active at every barrier-step (perfect balance).
// Each wave owns 16 q-rows (1 fragment) -> per-tile serial chain ~halved vs
// r5's 2-wave/32-row split, and residency doubles to ~16 waves/CU (4/SIMD).
// Double-buffered K/V, counted vmcnt; swapped-QK in-register softmax;
// defer-max (THR=8). LDS 32KB. XCD-local (h,b) decode.
__global__ __launch_bounds__(256, 4) void attn_kernel(const __bf16* __restrict__ qkv,
                                                      const __bf16* __restrict__ Vt,
                                                      __bf16* __restrict__ Y) {
  __shared__ __bf16 lK[2][64 * 64];
  __shared__ __bf16 lV[2][64 * 64];
  int tid = threadIdx.x, lane = tid & 63, w = tid >> 6;  // w in 0..3
  int q = lane & 15, g = lane >> 4;

  // XCD-aware decode: l -> (p, h, b); all 16 p-blocks of one (h,b) per XCD
  int l = blockIdx.x;
  int pairHB = ((l & 7) << 3) | (l >> 7);
  int p = (l >> 3) & 15;
  int h = pairHB & 15, b = pairHB >> 4;

  const float SCALE = 0.125f * 1.44269504088896f;  // 1/sqrt(64) * log2(e)
  const f32x4 fzero = {0.f, 0.f, 0.f, 0.f};

#pragma unroll 1
  for (int pass = 0; pass < 2; ++pass) {
    int qt = pass ? p : 31 - p;

    // Q fragment (B operand): wave w owns q-rows qt*64 + w*16 + q, prescaled
    const __bf16* qp = qkv + (size_t)(b * T_SEQ + qt * 64 + w * 16 + q) * 3072 + h * HD;
    bf16x8 qf[2];
    qf[0] = *(const bf16x8*)(qp + g * 8);
    qf[1] = *(const bf16x8*)(qp + 32 + g * 8);
#pragma unroll
    for (int kk = 0; kk < 2; ++kk)
#pragma unroll
      for (int jj = 0; jj < 8; ++jj) qf[kk][jj] = (__bf16)((float)qf[kk][jj] * SCALE);

    float m = -INFINITY, lsum = 0.f;
    f32x4 yacc[4];
#pragma unroll
    for (int f = 0; f < 4; ++f) yacc[f] = fzero;

    // drain Q loads / prior-pass stores so vmcnt accounting is exact
    asm volatile("s_waitcnt vmcnt(0)" ::: "memory");
    __builtin_amdgcn_sched_barrier(0);

    auto STAGE = [&](int kvt, int bi) {
#pragma unroll
      for (int it = 0; it < 2; ++it) {
        int o = it * 4096 + tid * 16;
        int row = o >> 7;
        int ss = ((o >> 4) & 7) ^ (row & 7);
        gload_lds16(qkv + (size_t)(b * T_SEQ + kvt * 64 + row) * 3072 + 1024 + h * HD + ss * 8,
                    (char*)lK[bi] + o);
        gload_lds16(Vt + (size_t)((b * NH + h) * HD + row) * T_SEQ + kvt * 64 + ss * 8,
                    (char*)lV[bi] + o);
      }
    };

    STAGE(0, 0);

#pragma unroll 1
    for (int kvt = 0; kvt <= qt; ++kvt) {
      int cur = kvt & 1;
      if (kvt < qt) {
        STAGE(kvt + 1, cur ^ 1);
        asm volatile("s_waitcnt vmcnt(4)" ::: "memory");  // cur landed; prefetch in flight
      } else {
        asm volatile("s_waitcnt vmcnt(0)" ::: "memory");
      }
      __builtin_amdgcn_sched_barrier(0);
      __builtin_amdgcn_s_barrier();
      __builtin_amdgcn_sched_barrier(0);

      // ---- S^T = K Q^T : s[f][r] = S[q-row q][kv = f*16 + g*4 + r] ----
      f32x4 s[4];
#pragma unroll
      for (int f = 0; f < 4; ++f) s[f] = fzero;
      const char* Kbase = (const char*)lK[cur];
      __builtin_amdgcn_s_setprio(1);
#pragma unroll
      for (int kk = 0; kk < 2; ++kk)
#pragma unroll
        for (int f = 0; f < 4; ++f) {
          int rk = f * 16 + q;
          int sk = (g + kk * 4) ^ (rk & 7);
          bf16x8 kf = *(const bf16x8*)(Kbase + rk * 128 + sk * 16);
          s[f] = __builtin_amdgcn_mfma_f32_16x16x32_bf16(kf, qf[kk], s[f], 0, 0, 0);
        }
      __builtin_amdgcn_s_setprio(0);

      // ---- causal mask (diagonal tile only) ----
      if (kvt == qt) {
        int qloc = w * 16 + q;
#pragma unroll
        for (int f = 0; f < 4; ++f)
#pragma unroll
          for (int r = 0; r < 4; ++r)
            if (f * 16 + g * 4 + r > qloc) s[f][r] = -INFINITY;
      }

      // ---- row max (local tree + 2 shfl) ----
      float mx = fmaxf(fmaxf(fmaxf(s[0][0], s[0][1]), fmaxf(s[0][2], s[0][3])),
                       fmaxf(fmaxf(s[1][0], s[1][1]), fmaxf(s[1][2], s[1][3])));
      mx = fmaxf(mx, fmaxf(fmaxf(fmaxf(s[2][0], s[2][1]), fmaxf(s[2][2], s[2][3])),
                           fmaxf(fmaxf(s[3][0], s[3][1]), fmaxf(s[3][2], s[3][3]))));
      mx = fmaxf(mx, __shfl_xor(mx, 16, 64));
      mx = fmaxf(mx, __shfl_xor(mx, 32, 64));

      // ---- defer-max rescale: only when growth exceeds THR=8 ----
      if (__any(mx - m > 8.0f)) {
        float mn = fmaxf(m, mx);
        float al = exp2f(m - mn);
        m = mn;
        lsum *= al;
#pragma unroll
        for (int r = 0; r < 4; ++r) {
          float ar = __shfl(al, g * 4 + r, 64);
#pragma unroll
          for (int f = 0; f < 4; ++f) yacc[f][r] *= ar;
        }
      }

      // ---- P = exp2(S - m), packed to bf16 words ----
      float ps = 0.f;
      unsigned int Wd[4][2];
#pragma unroll
      for (int f = 0; f < 4; ++f)
#pragma unroll
        for (int hh = 0; hh < 2; ++hh) {
          float e0 = exp2f(s[f][2 * hh] - m);
          float e1 = exp2f(s[f][2 * hh + 1] - m);
          ps += e0 + e1;
          Wd[f][hh] = pack_bf16_2(e0, e1);
        }
      lsum += ps;

      // ---- redistribute P words into PV A-operand frags ----
      int srcA = ((g & 1) << 5) | q;
      int srcB = srcA + 16;
      bool hisel = (g >= 2);
      bf16x8 pa[2];
#pragma unroll
      for (int kk = 0; kk < 2; ++kk) {
        unsigned int pw[4];
#pragma unroll
        for (int t = 0; t < 4; ++t) {
          int src = (t < 2) ? srcA : srcB;
          unsigned int c0 = (unsigned int)__shfl((int)Wd[2 * kk][t & 1], src, 64);
          unsigned int c1 = (unsigned int)__shfl((int)Wd[2 * kk + 1][t & 1], src, 64);
          pw[t] = hisel ? c1 : c0;
        }
        uint4 u = make_uint4(pw[0], pw[1], pw[2], pw[3]);
        pa[kk] = __builtin_bit_cast(bf16x8, u);
      }

      // ---- O += P V ----
      const char* Vbase = (const char*)lV[cur];
      __builtin_amdgcn_s_setprio(1);
#pragma unroll
      for (int kk = 0; kk < 2; ++kk)
#pragma unroll
        for (int f = 0; f < 4; ++f) {
          int rv = f * 16 + q;
          int sv2 = (g + kk * 4) ^ (rv & 7);
          bf16x8 vf = *(const bf16x8*)(Vbase + rv * 128 + sv2 * 16);
          yacc[f] = __builtin_amdgcn_mfma_f32_16x16x32_bf16(pa[kk], vf, yacc[f], 0, 0, 0);
        }
      __builtin_amdgcn_s_setprio(0);

      // all waves done reading cur before next iter's STAGE overwrites the other buffer
      __builtin_amdgcn_sched_barrier(0);
      asm volatile("s_waitcnt lgkmcnt(0)" ::: "memory");
      __builtin_amdgcn_s_barrier();
      __builtin_amdgcn_sched_barrier(0);
    }

    // ---- epilogue: reduce lsum, redistribute to O rows, store ----
    float ls = lsum;
    ls += __shfl_xor(ls, 16, 64);
    ls += __shfl_xor(ls, 32, 64);
    float linv = 1.0f / ls;
    int qrow = qt * 64 + w * 16 + g * 4;
#pragma unroll
    for (int r = 0; r < 4; ++r) {
      float lr = __shfl(linv, g * 4 + r, 64);
#pragma unroll
      for (int f = 0; f < 4; ++f) {
        Y[(size_t)(b * T_SEQ + qrow + r) * D_MODEL + h * HD + f * 16 + q] =
            (__bf16)(yacc[f][r] * lr);
      }
    }
  }
}

// ---------------- launcher ----------------
extern "C" void kernel_launch(void* const* d_in, const int* in_sizes, int n_in,
                              void* d_out, int out_size, void* d_ws, size_t ws_size,
                              hipStream_t stream) {
  const float* x = (const float*)d_in[0];      // [4,2048,1024]
  const float* Wqkv = (const float*)d_in[1];   // [1024,3072]
  const float* Wproj = (const float*)d_in[2];  // [1024,1024]
  float* out = (float*)d_out;                  // [4,2048,1024]
  char* ws = (char*)d_ws;

  __bf16* Xbf     = (__bf16*)(ws);                       // 16.78 MB
  __bf16* Wqkv_t  = (__bf16*)(ws + 16777216);            // 6.29 MB  [3072][1024]
  __bf16* Wproj_t = (__bf16*)(ws + 23068672);            // 2.10 MB  [1024][1024]
  __bf16* QKV     = (__bf16*)(ws + 25165824);            // 50.33 MB [8192][3072]
  __bf16* Vt      = (__bf16*)(ws + 75497472);            // 16.78 MB [(b,h,dv)][2048]
  __bf16* Yb      = (__bf16*)(ws + 92274688);            // 16.78 MB [8192][1024]

  cvt_bf16_kernel<<<4096, 256, 0, stream>>>(x, Xbf, NB * T_SEQ * D_MODEL);
  transpose_cvt_kernel<<<dim3(96, 32), dim3(32, 8), 0, stream>>>(Wqkv, Wqkv_t, 1024, 3072);
  transpose_cvt_kernel<<<dim3(32, 32), dim3(32, 8), 0, stream>>>(Wproj, Wproj_t, 1024, 1024);
  gemm_bt<__bf16><<<dim3(24, 64), 256, 0, stream>>>(Xbf, Wqkv_t, QKV, 8192, 3072, 1024);
  extract_vt_kernel<<<dim3(64, 2, 64), dim3(32, 8), 0, stream>>>(QKV, Vt);
  attn_kernel<<<1024, 256, 0, stream>>>(QKV, Vt, Yb);
  gemm_bt<float><<<dim3(8, 64), 256, 0, stream>>>(Yb, Wproj_t, out, 8192, 1024, 1024);
}